// Round 4
// baseline (264.712 us; speedup 1.0000x reference)
//
#include <hip/hip_runtime.h>

#define NN 2048
#define NE 8192
#define ED 10
#define EH 32
#define HID 160
#define KT 5440          // 160*34 : k = i*34+q ; q<32: w2, q=32: b2, q=33: root
#define KS 10            // split-K: 10 slices of 544 (= 16 i's, 17 mfma steps)
#define KSL 544
#define MT 32            // nodes per block tile
#define APAD 552         // A-tile row stride (544 + 8 pad: 2-way-free banks)
#define NNH (NN * HID)   // 327680

typedef __attribute__((ext_vector_type(8))) short short8;
typedef __attribute__((ext_vector_type(4))) float f32x4;
typedef unsigned int u32;

__device__ __forceinline__ ushort f2bf(float v) {   // RNE
    u32 u = __float_as_uint(v);
    u += 0x7FFF + ((u >> 16) & 1);
    return (ushort)(u >> 16);
}
__device__ __forceinline__ float bf2f(ushort u) {
    return __uint_as_float(((u32)u) << 16);
}
__device__ __forceinline__ u32 packbf(float lo, float hi) {
    return ((u32)f2bf(hi) << 16) | f2bf(lo);
}
__device__ __forceinline__ void gl2lds16(const ushort* g, ushort* l) {
    __builtin_amdgcn_global_load_lds(
        (const __attribute__((address_space(1))) u32*)g,
        (__attribute__((address_space(3))) u32*)l, 16, 0, 0);
}

// x at (node, i) for this layer: layer0 = raw x; else relu(bias + sum of Cp slices)
__device__ __forceinline__ float gatherx(const float* __restrict__ x0,
                                         const float* __restrict__ cpin,
                                         float biasv, int node, int i) {
    if (x0) return x0[node * HID + i];
    float s = biasv;
#pragma unroll
    for (int p = 0; p < KS; ++p) s += cpin[(size_t)p * NNH + node * HID + i];
    return fmaxf(s, 0.f);
}

// ================= prep: edge MLP (2 sets), WcatT build, CSR =================
__global__ __launch_bounds__(256) void k_prep(
        const float* __restrict__ ea,
        const float* __restrict__ w1a, const float* __restrict__ b1a,
        const float* __restrict__ w1b, const float* __restrict__ b1b,
        float* __restrict__ ha, float* __restrict__ hb,
        const float* __restrict__ w2a, const float* __restrict__ b2a,
        const float* __restrict__ roota,
        const float* __restrict__ w2b, const float* __restrict__ b2b,
        const float* __restrict__ rootb,
        ushort* __restrict__ WcA, ushort* __restrict__ WcB,
        const int* __restrict__ ei, int* __restrict__ doff,
        int* __restrict__ degg, float* __restrict__ dinv,
        int* __restrict__ delist) {
    __shared__ __align__(16) char smem[21760];
    int b = blockIdx.x, t = threadIdx.x;

    if (b < 512) {                       // ---- h = relu(ea@w1+b1), 4 elems/thread
        int set = b >> 8, rel = b & 255;
        const float* w1 = set ? w1b : w1a;
        const float* b1 = set ? b1b : b1a;
        float* h = set ? hb : ha;
        int idx = rel * 1024 + t * 4;
        int e = idx >> 5, j0 = idx & 31;
        float o4[4];
#pragma unroll
        for (int u = 0; u < 4; ++u) {
            float acc = b1[j0 + u];
#pragma unroll
            for (int i = 0; i < ED; ++i) acc += ea[e * ED + i] * w1[i * EH + j0 + u];
            o4[u] = fmaxf(acc, 0.f);
        }
        *(float4*)&h[idx] = *(const float4*)o4;
        return;
    }
    if (b < 672) {                       // ---- WcatT[o][i*34+q] bf16, LDS-coalesced
        int rel = b - 512;               // 0..159
        int set = rel / 80, i0 = (rel % 80) * 2;
        u32 (*tile)[34] = (u32(*)[34])smem;   // [160 o][34 u32]
        const float* w2 = set ? w2b : w2a;
        const float* b2 = set ? b2b : b2a;
        const float* root = set ? rootb : roota;
        ushort* W = set ? WcB : WcA;
        if (t < HID) {
#pragma unroll
            for (int di = 0; di < 2; ++di) {
                int i = i0 + di;
#pragma unroll
                for (int p = 0; p < 16; ++p) {
                    float v0 = w2[(size_t)(2 * p) * 25600 + i * HID + t];
                    float v1 = w2[(size_t)(2 * p + 1) * 25600 + i * HID + t];
                    tile[t][di * 17 + p] = packbf(v0, v1);
                }
                tile[t][di * 17 + 16] = packbf(b2[i * HID + t], root[i * HID + t]);
            }
        }
        __syncthreads();
        u32* dst = (u32*)W;
        for (int w = t; w < 5440; w += 256) {   // coalesced: 34 consecutive u32/row
            int o = w / 34, j = w - o * 34;
            dst[(size_t)o * 2720 + i0 * 17 + j] = tile[o][j];
        }
        return;
    }
    // ---- CSR build over dst (single block, 256 threads)
    int* deg = (int*)smem;               // NN
    int* cur = deg + NN;                 // NN
    int* part = cur + NN;                // 256
    for (int i = t; i < NN; i += 256) deg[i] = 0;
    __syncthreads();
    for (int e = t; e < NE; e += 256) atomicAdd(&deg[ei[NE + e]], 1);
    __syncthreads();
    int loc[8], s = 0;
#pragma unroll
    for (int i = 0; i < 8; ++i) { loc[i] = s; s += deg[t * 8 + i]; }
    part[t] = s;
    __syncthreads();
    int tot = s;
    for (int st = 1; st < 256; st <<= 1) {
        int v = (t >= st) ? part[t - st] : 0;
        __syncthreads();
        part[t] += v;
        __syncthreads();
    }
    int base = part[t] - tot;
#pragma unroll
    for (int i = 0; i < 8; ++i) {
        int d = t * 8 + i;
        doff[d] = base + loc[i];
        cur[d] = base + loc[i];
        degg[d] = deg[d];
        dinv[d] = 1.0f / fmaxf((float)deg[d], 1.0f);
    }
    __syncthreads();
    for (int e = t; e < NE; e += 256) {
        int d = ei[NE + e];
        int p = atomicAdd(&cur[d], 1);
        delist[p] = e;
    }
}

// ======= fused layer: build A-tile (32 nodes x 544 k) in LDS, GEMM vs Wc =======
// grid (64 bm, 10 ks). Reads prev layer as raw Cp slices (reader-side split-K sum).
__global__ __launch_bounds__(256) void k_layer(
        const float* __restrict__ x0,       // layer0 input (else null)
        const float* __restrict__ cpin,     // prev layer partials (else null)
        const float* __restrict__ bprev,    // prev layer bias (else null)
        const float* __restrict__ h, const ushort* __restrict__ wc,
        const int* __restrict__ ei, const int* __restrict__ doff,
        const int* __restrict__ degg, const float* __restrict__ dinv,
        const int* __restrict__ delist, float* __restrict__ cpout) {
    __shared__ __align__(16) ushort sA[MT * APAD];        // 35328 B
    __shared__ __align__(16) ushort sB[2][160 * 32];      // 20480 B
    __shared__ float hbuf[128 * 33];                      // 16896 B
    __shared__ int ebuf[128], sbuf[128];                  // 1024 B
    int t = threadIdx.x;
    int bm = blockIdx.x, ks = blockIdx.y;
    int d0 = bm * MT, i0 = ks * 16;
    int e0 = doff[d0];
    int e1 = (d0 + MT < NN) ? doff[d0 + MT] : NE;

    // ---------- phase A: per-cell (d, i) accumulation ----------
    int il = t & 15, i = i0 + il;
    int dA = d0 + (t >> 4), dB = dA + 16;
    float biasv = x0 ? 0.f : bprev[i];
    int aLo = doff[dA], aHi = aLo + degg[dA];
    int bLo = doff[dB], bHi = bLo + degg[dB];
    float accA[33], accB[33];
#pragma unroll
    for (int q = 0; q < 33; ++q) { accA[q] = 0.f; accB[q] = 0.f; }

    for (int c0 = e0; c0 < e1; c0 += 128) {
        int nc = min(128, e1 - c0);
        __syncthreads();                 // protect ebuf/sbuf/hbuf reuse
        if (t < nc) {
            int e = delist[c0 + t];
            ebuf[t] = e;
            sbuf[t] = ei[e];             // src
        }
        __syncthreads();
        for (int idx = t; idx < nc * 32; idx += 256)
            hbuf[(idx >> 5) * 33 + (idx & 31)] =
                h[(size_t)ebuf[idx >> 5] * EH + (idx & 31)];
        __syncthreads();
        int jl = max(aLo, c0) - c0, jh = min(aHi, c0 + nc) - c0;
        for (int j = jl; j < jh; ++j) {
            float xs = gatherx(x0, cpin, biasv, sbuf[j], i);
            const float* hj = &hbuf[j * 33];
#pragma unroll
            for (int q = 0; q < 32; ++q) accA[q] += hj[q] * xs;
            accA[32] += xs;
        }
        jl = max(bLo, c0) - c0; jh = min(bHi, c0 + nc) - c0;
        for (int j = jl; j < jh; ++j) {
            float xs = gatherx(x0, cpin, biasv, sbuf[j], i);
            const float* hj = &hbuf[j * 33];
#pragma unroll
            for (int q = 0; q < 32; ++q) accB[q] += hj[q] * xs;
            accB[32] += xs;
        }
    }
    float rootA = gatherx(x0, cpin, biasv, dA, i);
    float rootB = gatherx(x0, cpin, biasv, dB, i);

    // ---------- stage first Wc k-step while writing A-tile ----------
    auto stage = [&](int buf, int c) {
        size_t k0 = (size_t)ks * KSL + c * 32;
#pragma unroll
        for (int q = 0; q < 2; ++q) {     // 160x32 bf16 = 640 x 16B
            int s = t + q * 256;
            int r = s >> 2, go = (s & 3) * 8;
            gl2lds16(&wc[(size_t)r * KT + k0 + go], &sB[buf][s * 8]);
        }
        if (t < 128) {
            int s = t + 512;
            int r = s >> 2, go = (s & 3) * 8;
            gl2lds16(&wc[(size_t)r * KT + k0 + go], &sB[buf][s * 8]);
        }
    };
    stage(0, 0);

    {
        float diA = dinv[dA], diB = dinv[dB];
        u32* pa = (u32*)&sA[(t >> 4) * APAD + il * 34];
        u32* pb = (u32*)&sA[((t >> 4) + 16) * APAD + il * 34];
#pragma unroll
        for (int p = 0; p < 16; ++p) {
            pa[p] = packbf(accA[2 * p] * diA, accA[2 * p + 1] * diA);
            pb[p] = packbf(accB[2 * p] * diB, accB[2 * p + 1] * diB);
        }
        pa[16] = packbf(accA[32] * diA, rootA);
        pb[16] = packbf(accB[32] * diB, rootB);
    }
    __syncthreads();   // A-tile visible + sB[0] staged (barrier drains vmcnt)

    // ---------- phase B: 17-step double-buffered MFMA ----------
    int wid = t >> 6, lane = t & 63;
    int wm = (wid >> 1) * 16, wn = (wid & 1) * 80;
    int lr = lane & 15, lk = lane >> 4;
    f32x4 acc[5];
#pragma unroll
    for (int j = 0; j < 5; ++j) acc[j] = (f32x4){0.f, 0.f, 0.f, 0.f};

    for (int c = 0; c < 17; ++c) {
        int cur = c & 1;
        if (c + 1 < 17) stage(cur ^ 1, c + 1);   // prefetch hides under MFMA
        short8 av = *(const short8*)&sA[(wm + lr) * APAD + c * 32 + lk * 8];
        short8 bv[5];
#pragma unroll
        for (int nt = 0; nt < 5; ++nt)
            bv[nt] = *(const short8*)&sB[cur][(wn + nt * 16 + lr) * 32 + lk * 8];
#pragma unroll
        for (int nt = 0; nt < 5; ++nt)
            acc[nt] = __builtin_amdgcn_mfma_f32_16x16x32_bf16(av, bv[nt], acc[nt], 0, 0, 0);
        __syncthreads();
    }

    float* Cb = cpout + (size_t)ks * NNH;
#pragma unroll
    for (int nt = 0; nt < 5; ++nt) {
        int n = wn + nt * 16 + lr;
        int m0 = d0 + wm + lk * 4;
#pragma unroll
        for (int r = 0; r < 4; ++r)
            Cb[(size_t)(m0 + r) * HID + n] = acc[nt][r];
    }
}

// ====== final: out = bias + sum of Cp slices (f32, no relu) ======
__global__ __launch_bounds__(256) void k_fin(const float* __restrict__ Cp,
                                             const float* __restrict__ bias,
                                             float* __restrict__ out) {
    int base = (blockIdx.x * 256 + threadIdx.x) * 4;   // < 327680
    float4 s = *(const float4*)&bias[base % HID];
#pragma unroll
    for (int p = 0; p < KS; ++p) {
        float4 v = *(const float4*)&Cp[(size_t)p * NNH + base];
        s.x += v.x; s.y += v.y; s.z += v.z; s.w += v.w;
    }
    *(float4*)&out[base] = s;
}

extern "C" void kernel_launch(void* const* d_in, const int* in_sizes, int n_in,
                              void* d_out, int out_size, void* d_ws, size_t ws_size,
                              hipStream_t stream) {
    const float* x     = (const float*)d_in[0];
    const float* ea    = (const float*)d_in[1];
    const float* w1a   = (const float*)d_in[2];
    const float* b1a   = (const float*)d_in[3];
    const float* w2a   = (const float*)d_in[4];
    const float* b2a   = (const float*)d_in[5];
    const float* roota = (const float*)d_in[6];
    const float* biasa = (const float*)d_in[7];
    const float* w1b   = (const float*)d_in[8];
    const float* b1b   = (const float*)d_in[9];
    const float* w2b   = (const float*)d_in[10];
    const float* b2b   = (const float*)d_in[11];
    const float* rootb = (const float*)d_in[12];
    const float* biasb = (const float*)d_in[13];
    const int*   ei    = (const int*)d_in[14];
    float* out = (float*)d_out;

    char* p = (char*)d_ws;
    float* Cp0  = (float*)p;   p += (size_t)KS * NNH * 4;   // 13.1 MB
    float* Cp1  = (float*)p;   p += (size_t)KS * NNH * 4;   // 13.1 MB
    ushort* WcA = (ushort*)p;  p += (size_t)HID * KT * 2;   // 1.74 MB
    ushort* WcB = (ushort*)p;  p += (size_t)HID * KT * 2;
    float* h_a  = (float*)p;   p += (size_t)NE * EH * 4;
    float* h_b  = (float*)p;   p += (size_t)NE * EH * 4;
    int* doff   = (int*)p;     p += NN * 4;
    int* degg   = (int*)p;     p += NN * 4;
    float* dinv = (float*)p;   p += NN * 4;
    int* delist = (int*)p;     p += NE * 4;

    k_prep<<<673, 256, 0, stream>>>(ea, w1a, b1a, w1b, b1b, h_a, h_b,
                                    w2a, b2a, roota, w2b, b2b, rootb, WcA, WcB,
                                    ei, doff, degg, dinv, delist);

    dim3 lg(NN / MT, KS);
    // layer 0: reads x, writes Cp0
    k_layer<<<lg, 256, 0, stream>>>(x, nullptr, nullptr, h_a, WcA,
                                    ei, doff, degg, dinv, delist, Cp0);
    // layer 1: reads Cp0 (+biasa, relu), writes Cp1
    k_layer<<<lg, 256, 0, stream>>>(nullptr, Cp0, biasa, h_b, WcB,
                                    ei, doff, degg, dinv, delist, Cp1);
    // layer 2: reads Cp1 (+biasb, relu), writes Cp0
    k_layer<<<lg, 256, 0, stream>>>(nullptr, Cp1, biasb, h_b, WcB,
                                    ei, doff, degg, dinv, delist, Cp0);
    // final: out = biasb + sum Cp0
    k_fin<<<NNH / 1024, 256, 0, stream>>>(Cp0, biasb, out);
}

// Round 5
// 227.255 us; speedup vs baseline: 1.1648x; 1.1648x over previous
//
#include <hip/hip_runtime.h>

#define NN 2048
#define NE 8192
#define ED 10
#define EH 32
#define HID 160
#define KT 5440          // 160*34 : k = i*34+q ; q<32: w2, q=32: b2, q=33: root
#define KS 10            // split-K: 10 slices of 544 (= 16 i's, 17 mfma steps)
#define KSL 544
#define MT 32            // nodes per block tile
#define APAD 552         // A-tile row stride (544+8): 2-way-free banks on reads
#define NNH (NN * HID)   // 327680

typedef __attribute__((ext_vector_type(8))) short short8;
typedef __attribute__((ext_vector_type(4))) float f32x4;
typedef unsigned int u32;

__device__ __forceinline__ ushort f2bf(float v) {   // RNE
    u32 u = __float_as_uint(v);
    u += 0x7FFF + ((u >> 16) & 1);
    return (ushort)(u >> 16);
}
__device__ __forceinline__ u32 packbf(float lo, float hi) {
    return ((u32)f2bf(hi) << 16) | f2bf(lo);
}
__device__ __forceinline__ void gl2lds16(const ushort* g, ushort* l) {
    __builtin_amdgcn_global_load_lds(
        (const __attribute__((address_space(1))) u32*)g,
        (__attribute__((address_space(3))) u32*)l, 16, 0, 0);
}

// ====== prep: edge MLP (2 sets), WcatT build, bias-init of accumulators, CSR ======
// blocks [0,512): MLP; [512,672): WcatT; [672,912): bias-init; 912: CSR
__global__ __launch_bounds__(256) void k_prep(
        const float* __restrict__ ea,
        const float* __restrict__ w1a, const float* __restrict__ b1a,
        const float* __restrict__ w1b, const float* __restrict__ b1b,
        float* __restrict__ ha, float* __restrict__ hb,
        const float* __restrict__ w2a, const float* __restrict__ b2a,
        const float* __restrict__ roota,
        const float* __restrict__ w2b, const float* __restrict__ b2b,
        const float* __restrict__ rootb,
        ushort* __restrict__ WcA, ushort* __restrict__ WcB,
        const float* __restrict__ biasa, const float* __restrict__ biasb,
        float* __restrict__ xacc0, float* __restrict__ xacc1,
        float* __restrict__ outb,
        const int* __restrict__ ei, int* __restrict__ doff,
        int* __restrict__ degg, float* __restrict__ dinv,
        int* __restrict__ delist) {
    __shared__ __align__(16) char smem[21760];
    int b = blockIdx.x, t = threadIdx.x;

    if (b < 512) {                       // ---- h = relu(ea@w1+b1), 4 elems/thread
        int set = b >> 8, rel = b & 255;
        const float* w1 = set ? w1b : w1a;
        const float* b1 = set ? b1b : b1a;
        float* h = set ? hb : ha;
        int idx = rel * 1024 + t * 4;
        int e = idx >> 5, j0 = idx & 31;
        float o4[4];
#pragma unroll
        for (int u = 0; u < 4; ++u) {
            float acc = b1[j0 + u];
#pragma unroll
            for (int i = 0; i < ED; ++i) acc += ea[e * ED + i] * w1[i * EH + j0 + u];
            o4[u] = fmaxf(acc, 0.f);
        }
        *(float4*)&h[idx] = *(const float4*)o4;
        return;
    }
    if (b < 672) {                       // ---- WcatT[o][i*34+q] bf16, LDS-coalesced
        int rel = b - 512;               // 0..159
        int set = rel / 80, i0 = (rel % 80) * 2;
        u32 (*tile)[34] = (u32(*)[34])smem;   // [160 o][34 u32]
        const float* w2 = set ? w2b : w2a;
        const float* b2 = set ? b2b : b2a;
        const float* root = set ? rootb : roota;
        ushort* W = set ? WcB : WcA;
        if (t < HID) {
#pragma unroll
            for (int di = 0; di < 2; ++di) {
                int i = i0 + di;
#pragma unroll
                for (int p = 0; p < 16; ++p) {
                    float v0 = w2[(size_t)(2 * p) * 25600 + i * HID + t];
                    float v1 = w2[(size_t)(2 * p + 1) * 25600 + i * HID + t];
                    tile[t][di * 17 + p] = packbf(v0, v1);
                }
                tile[t][di * 17 + 16] = packbf(b2[i * HID + t], root[i * HID + t]);
            }
        }
        __syncthreads();
        u32* dst = (u32*)W;
        for (int w = t; w < 5440; w += 256) {   // coalesced: 34 consecutive u32/row
            int o = w / 34, j = w - o * 34;
            dst[(size_t)o * 2720 + i0 * 17 + j] = tile[o][j];
        }
        return;
    }
    if (b < 912) {                       // ---- bias-init of the 3 accumulators
        int jb = b - 672;                // 0..239
        int buf = jb / 80, rel = jb % 80;
        float* dst = buf == 0 ? xacc0 : (buf == 1 ? xacc1 : outb);
        const float* bias = buf == 0 ? biasa : biasb;
        int base = rel * 4096 + t * 16;
#pragma unroll
        for (int k = 0; k < 4; ++k) {
            int idx = base + k * 4;
            *(float4*)&dst[idx] = *(const float4*)&bias[idx % HID];
        }
        return;
    }
    // ---- CSR build over dst (single block, 256 threads)
    int* deg = (int*)smem;               // NN
    int* cur = deg + NN;                 // NN
    int* part = cur + NN;                // 256
    for (int i = t; i < NN; i += 256) deg[i] = 0;
    __syncthreads();
    for (int e = t; e < NE; e += 256) atomicAdd(&deg[ei[NE + e]], 1);
    __syncthreads();
    int loc[8], s = 0;
#pragma unroll
    for (int i = 0; i < 8; ++i) { loc[i] = s; s += deg[t * 8 + i]; }
    part[t] = s;
    __syncthreads();
    int tot = s;
    for (int st = 1; st < 256; st <<= 1) {
        int v = (t >= st) ? part[t - st] : 0;
        __syncthreads();
        part[t] += v;
        __syncthreads();
    }
    int base = part[t] - tot;
#pragma unroll
    for (int i = 0; i < 8; ++i) {
        int d = t * 8 + i;
        doff[d] = base + loc[i];
        cur[d] = base + loc[i];
        degg[d] = deg[d];
        dinv[d] = 1.0f / fmaxf((float)deg[d], 1.0f);
    }
    __syncthreads();
    for (int e = t; e < NE; e += 256) {
        int d = ei[NE + e];
        int p = atomicAdd(&cur[d], 1);
        delist[p] = e;
    }
}

// ======= fused layer: build A-tile (32 nodes x 544 k) in LDS, GEMM vs Wc, =======
// ======= atomically accumulate into obuf (pre-initialized with bias).     =======
// grid (64 bm, 10 ks).
__global__ __launch_bounds__(256) void k_layer(
        const float* __restrict__ xin, int dorelu,
        const float* __restrict__ h, const ushort* __restrict__ wc,
        const int* __restrict__ ei, const int* __restrict__ doff,
        const int* __restrict__ degg, const float* __restrict__ dinv,
        const int* __restrict__ delist, float* __restrict__ obuf) {
    __shared__ __align__(16) ushort sA[MT * APAD];        // 35328 B
    __shared__ __align__(16) ushort sB[2][160 * 32];      // 20480 B
    int t = threadIdx.x;
    int bm = blockIdx.x, ks = blockIdx.y;
    int d0 = bm * MT, i0 = ks * 16;

    // B-slice stage: linear LDS dest, XOR-swizzled global source (slot=lk^((row>>1)&3))
    auto stage = [&](int buf, int c) {
        size_t k0 = (size_t)ks * KSL + c * 32;
#pragma unroll
        for (int q = 0; q < 2; ++q) {
            int s = t + q * 256;
            int row = s >> 2;
            int lkq = (s & 3) ^ ((row >> 1) & 3);
            gl2lds16(&wc[(size_t)row * KT + k0 + lkq * 8], &sB[buf][s * 8]);
        }
        if (t < 128) {
            int s = t + 512;
            int row = s >> 2;
            int lkq = (s & 3) ^ ((row >> 1) & 3);
            gl2lds16(&wc[(size_t)row * KT + k0 + lkq * 8], &sB[buf][s * 8]);
        }
    };
    stage(0, 0);       // issued at entry; completes under phase A

    // ---------- phase A: per-cell (d, i) accumulation, direct L2 reads ----------
    int il = t & 15, i = i0 + il;
    int dA = d0 + (t >> 4), dB = dA + 16;
    auto ldx = [&](int node) {
        float v = xin[node * HID + i];
        return dorelu ? fmaxf(v, 0.f) : v;
    };
    float accA[33], accB[33];
#pragma unroll
    for (int q = 0; q < 33; ++q) { accA[q] = 0.f; accB[q] = 0.f; }

    int aLo = doff[dA], aHi = aLo + degg[dA];
    for (int o = aLo; o < aHi; ++o) {
        int e = delist[o];
        float xs = ldx(ei[e]);
        const float4* hp = (const float4*)&h[(size_t)e * EH];
#pragma unroll
        for (int q8 = 0; q8 < 8; ++q8) {
            float4 hv = hp[q8];
            accA[q8 * 4 + 0] += hv.x * xs;
            accA[q8 * 4 + 1] += hv.y * xs;
            accA[q8 * 4 + 2] += hv.z * xs;
            accA[q8 * 4 + 3] += hv.w * xs;
        }
        accA[32] += xs;
    }
    int bLo = doff[dB], bHi = bLo + degg[dB];
    for (int o = bLo; o < bHi; ++o) {
        int e = delist[o];
        float xs = ldx(ei[e]);
        const float4* hp = (const float4*)&h[(size_t)e * EH];
#pragma unroll
        for (int q8 = 0; q8 < 8; ++q8) {
            float4 hv = hp[q8];
            accB[q8 * 4 + 0] += hv.x * xs;
            accB[q8 * 4 + 1] += hv.y * xs;
            accB[q8 * 4 + 2] += hv.z * xs;
            accB[q8 * 4 + 3] += hv.w * xs;
        }
        accB[32] += xs;
    }
    float rootA = ldx(dA), rootB = ldx(dB);

    {
        float diA = dinv[dA], diB = dinv[dB];
        u32* pa = (u32*)&sA[(t >> 4) * APAD + il * 34];
        u32* pb = (u32*)&sA[((t >> 4) + 16) * APAD + il * 34];
#pragma unroll
        for (int p = 0; p < 16; ++p) {
            pa[p] = packbf(accA[2 * p] * diA, accA[2 * p + 1] * diA);
            pb[p] = packbf(accB[2 * p] * diB, accB[2 * p + 1] * diB);
        }
        pa[16] = packbf(accA[32] * diA, rootA);
        pb[16] = packbf(accB[32] * diB, rootB);
    }
    __syncthreads();   // A-tile visible + sB[0] staged (barrier drains vmcnt)

    // ---------- phase B: 17-step double-buffered MFMA ----------
    int wid = t >> 6, lane = t & 63;
    int wm = (wid >> 1) * 16, wn = (wid & 1) * 80;
    int lr = lane & 15, lk = lane >> 4;
    f32x4 acc[5];
#pragma unroll
    for (int j = 0; j < 5; ++j) acc[j] = (f32x4){0.f, 0.f, 0.f, 0.f};

    for (int c = 0; c < 17; ++c) {
        int cur = c & 1;
        if (c + 1 < 17) stage(cur ^ 1, c + 1);   // prefetch hides under MFMA
        short8 av = *(const short8*)&sA[(wm + lr) * APAD + c * 32 + lk * 8];
        short8 bv[5];
#pragma unroll
        for (int nt = 0; nt < 5; ++nt) {
            int row = wn + nt * 16 + lr;
            bv[nt] = *(const short8*)&sB[cur][row * 32 +
                                             (lk ^ ((row >> 1) & 3)) * 8];
        }
#pragma unroll
        for (int nt = 0; nt < 5; ++nt)
            acc[nt] = __builtin_amdgcn_mfma_f32_16x16x32_bf16(av, bv[nt], acc[nt], 0, 0, 0);
        __syncthreads();
    }

    // ---------- epilogue: atomic accumulate into bias-initialized obuf ----------
#pragma unroll
    for (int nt = 0; nt < 5; ++nt) {
        int n = wn + nt * 16 + lr;
        int m0 = d0 + wm + lk * 4;
#pragma unroll
        for (int r = 0; r < 4; ++r)
            unsafeAtomicAdd(&obuf[(size_t)(m0 + r) * HID + n], acc[nt][r]);
    }
}

extern "C" void kernel_launch(void* const* d_in, const int* in_sizes, int n_in,
                              void* d_out, int out_size, void* d_ws, size_t ws_size,
                              hipStream_t stream) {
    const float* x     = (const float*)d_in[0];
    const float* ea    = (const float*)d_in[1];
    const float* w1a   = (const float*)d_in[2];
    const float* b1a   = (const float*)d_in[3];
    const float* w2a   = (const float*)d_in[4];
    const float* b2a   = (const float*)d_in[5];
    const float* roota = (const float*)d_in[6];
    const float* biasa = (const float*)d_in[7];
    const float* w1b   = (const float*)d_in[8];
    const float* b1b   = (const float*)d_in[9];
    const float* w2b   = (const float*)d_in[10];
    const float* b2b   = (const float*)d_in[11];
    const float* rootb = (const float*)d_in[12];
    const float* biasb = (const float*)d_in[13];
    const int*   ei    = (const int*)d_in[14];
    float* out = (float*)d_out;

    char* p = (char*)d_ws;
    float* xacc0 = (float*)p;  p += (size_t)NNH * 4;        // 1.31 MB
    float* xacc1 = (float*)p;  p += (size_t)NNH * 4;
    ushort* WcA  = (ushort*)p; p += (size_t)HID * KT * 2;   // 1.74 MB
    ushort* WcB  = (ushort*)p; p += (size_t)HID * KT * 2;
    float* h_a   = (float*)p;  p += (size_t)NE * EH * 4;
    float* h_b   = (float*)p;  p += (size_t)NE * EH * 4;
    int* doff    = (int*)p;    p += NN * 4;
    int* degg    = (int*)p;    p += NN * 4;
    float* dinv  = (float*)p;  p += NN * 4;
    int* delist  = (int*)p;    p += NE * 4;

    k_prep<<<913, 256, 0, stream>>>(ea, w1a, b1a, w1b, b1b, h_a, h_b,
                                    w2a, b2a, roota, w2b, b2b, rootb, WcA, WcB,
                                    biasa, biasb, xacc0, xacc1, out,
                                    ei, doff, degg, dinv, delist);

    dim3 lg(NN / MT, KS);
    // layer 0: reads x (raw), accumulates into xacc0 (init = biasa)
    k_layer<<<lg, 256, 0, stream>>>(x, 0, h_a, WcA,
                                    ei, doff, degg, dinv, delist, xacc0);
    // layer 1: reads relu(xacc0), accumulates into xacc1 (init = biasb)
    k_layer<<<lg, 256, 0, stream>>>(xacc0, 1, h_b, WcB,
                                    ei, doff, degg, dinv, delist, xacc1);
    // layer 2: reads relu(xacc1), accumulates into out (init = biasb)
    k_layer<<<lg, 256, 0, stream>>>(xacc1, 1, h_b, WcB,
                                    ei, doff, degg, dinv, delist, out);
}